// Round 8
// baseline (802.415 us; speedup 1.0000x reference)
//
#include <hip/hip_runtime.h>
#include <hip/hip_bf16.h>

// MoE SwiGLU: H=2048, I=1408, E=8, TOPK=2, T=4096 tokens (8192 pairs).
// R8 = R7 (bf16 preconvert + global_load_lds + XCD-chunk swizzle, all verified)
//  + BK=32 named-two-buffer 2-phase pipeline (static LDS disjointness -> no
//    early vmcnt(0) drain; stage of next tile flies under current MFMA)
//  + occupancy bump: gemm1 3 blocks/CU (96 slots >= 88 real blocks/XCD),
//    gemm2 4 blocks/CU (128 slots == 128 real blocks/XCD) -> no tail rounds.

typedef __bf16 bf16;
typedef bf16 bf16x8 __attribute__((ext_vector_type(8)));
typedef float f32x4 __attribute__((ext_vector_type(4)));

constexpr int Hdim = 2048;
constexpr int Idim = 1408;
constexpr int NE = 8;
constexpr int TOPK = 2;
constexpr int NT = 4096;      // tokens
constexpr int NPAIR = 8192;   // T * TOPK

#define GLOAD16(G, L) __builtin_amdgcn_global_load_lds(                    \
    (const __attribute__((address_space(1))) void*)(G),                    \
    (__attribute__((address_space(3))) void*)(L), 16, 0, 0)

// ---------------- f32 -> bf16 convert (streaming) ----------------

__global__ void k_cvt(const float* __restrict__ src, bf16* __restrict__ dst, int n8) {
    int i = blockIdx.x * 256 + threadIdx.x;
    if (i >= n8) return;
    f32x4 a = *reinterpret_cast<const f32x4*>(src + (size_t)i * 8);
    f32x4 b = *reinterpret_cast<const f32x4*>(src + (size_t)i * 8 + 4);
    bf16x8 v;
#pragma unroll
    for (int j = 0; j < 4; j++) { v[j] = (bf16)a[j]; v[4 + j] = (bf16)b[j]; }
    *reinterpret_cast<bf16x8*>(dst + (size_t)i * 8) = v;
}

// ---------------- binning (deterministic) ----------------

__global__ void k_bin1(const int* __restrict__ eidx, int* __restrict__ chunkhist) {
    __shared__ int h[NE];
    int t = threadIdx.x;
    if (t < NE) h[t] = 0;
    __syncthreads();
    int p = blockIdx.x * 256 + t;
    atomicAdd(&h[eidx[p]], 1);
    __syncthreads();
    if (t < NE) chunkhist[blockIdx.x * NE + t] = h[t];
}

__global__ void k_bin2(int* __restrict__ meta, const int* __restrict__ chunkhist,
                       int* __restrict__ chunkbase) {
    if (threadIdx.x == 0) {
        int counts[NE];
        for (int e = 0; e < NE; e++) counts[e] = 0;
        for (int b = 0; b < 32; b++)
            for (int e = 0; e < NE; e++) {
                chunkbase[b * NE + e] = counts[e];
                counts[e] += chunkhist[b * NE + e];
            }
        int acc = 0;
        for (int e = 0; e < NE; e++) {
            meta[e] = counts[e];      // counts
            meta[8 + e] = acc;        // exclusive offsets
            acc += counts[e];
        }
    }
}

__global__ void k_bin3(const int* __restrict__ eidx, const float* __restrict__ wts,
                       const int* __restrict__ meta, const int* __restrict__ chunkbase,
                       int* __restrict__ token_id, float* __restrict__ weightv) {
    __shared__ int earr[256];
    int t = threadIdx.x;
    int p = blockIdx.x * 256 + t;
    int e = eidx[p];
    earr[t] = e;
    __syncthreads();
    int rank = 0;
    for (int q = 0; q < t; q++) rank += (earr[q] == e) ? 1 : 0;
    int pos = meta[8 + e] + chunkbase[blockIdx.x * NE + e] + rank;
    token_id[pos] = p / TOPK;
    weightv[pos] = wts[p];
}

// ---------------- GEMM1: gu = X_e * w13[e]^T, fused SwiGLU ----------------
// Flat grid 5632 = 64 m-slots x 11 y-tiles x 8 experts. XCD-chunk swizzle:
// work = (flat%8)*704 + flat/8 -> XCD k runs groups [11k, 11k+11) = expert k.
// BK=32, named dbuf (2 x 24KB), 3 blocks/CU.

__global__ __launch_bounds__(256, 3) void k_gemm1(
    const bf16* __restrict__ xb, const bf16* __restrict__ w13b,
    const int* __restrict__ meta, bf16* __restrict__ hact) {
    const int flat = blockIdx.x;
    const int work = (flat & 7) * 704 + (flat >> 3);
    const int mslot = work & 63;
    const int grp = work >> 6;        // [0,88)
    const int e = grp / 11;
    const int ytile = grp - e * 11;

    const int n_e = meta[e];
    const int m0 = mslot * 128;
    if (m0 >= n_e) return;
    const int base = meta[8 + e];
    const int* toks = (const int*)(meta + 64) + base;
    const bf16* wg = w13b + (size_t)e * (2 * Idim) * Hdim + (size_t)(ytile * 128) * Hdim;
    const bf16* wu = wg + (size_t)Idim * Hdim;

    // per buffer (elements): A [0,4096) | Bg [4096,8192) | Bu [8192,12288)
    __shared__ bf16 buf0[12288];
    __shared__ bf16 buf1[12288];

    const int tid = threadIdx.x;
    const int lane = tid & 63;
    const int wid = tid >> 6;
    const int wr = wid >> 1, wc = wid & 1;
    const int l16 = lane & 15, lq = lane >> 4;

    // staging: per matrix 512 slots of 16B (128 rows x 4 segs), 2 rounds x 256 thr.
    // LDS dest LINEAR (slot*16); global seg pre-swizzled: LDS seg s of row r
    // holds global seg s ^ ((r>>1)&3).
    const bf16* gp[6];
    int lo[6];
#pragma unroll
    for (int r = 0; r < 6; r++) {
        int rr = r & 1;
        int s = rr * 256 + tid;
        int row = s >> 2, seg = s & 3;
        int ss = seg ^ ((row >> 1) & 3);
        lo[r] = (r >> 1) * 8192 + (rr * 256 + (tid & ~63)) * 16;  // wave-uniform byte base
        if (r < 2) {
            int rm = m0 + row;
            if (rm >= n_e) rm = n_e - 1;          // clamp keeps reads in-bounds
            gp[r] = xb + (size_t)toks[rm] * Hdim + ss * 8;
        } else if (r < 4) {
            gp[r] = wg + (size_t)row * Hdim + ss * 8;
        } else {
            gp[r] = wu + (size_t)row * Hdim + ss * 8;
        }
    }

    f32x4 accg[4][4], accu[4][4];
#pragma unroll
    for (int m = 0; m < 4; m++)
#pragma unroll
        for (int n = 0; n < 4; n++) {
            accg[m][n] = f32x4{0.f, 0.f, 0.f, 0.f};
            accu[m][n] = f32x4{0.f, 0.f, 0.f, 0.f};
        }

#define STAGE1(BUF, K0)                                                     \
    {                                                                       \
        _Pragma("unroll")                                                   \
        for (int r = 0; r < 6; r++) GLOAD16(gp[r] + (K0), (char*)(BUF) + lo[r]); \
    }

#define COMP1(BUF)                                                          \
    {                                                                       \
        const bf16* As_ = (BUF);                                            \
        const bf16* Bg_ = (BUF) + 4096;                                     \
        const bf16* Bu_ = (BUF) + 8192;                                     \
        bf16x8 af[4], bgf[4], buf_[4];                                      \
        _Pragma("unroll")                                                   \
        for (int m = 0; m < 4; m++) {                                       \
            int row = wr * 64 + m * 16 + l16;                               \
            int s = lq ^ ((row >> 1) & 3);                                  \
            af[m] = *reinterpret_cast<const bf16x8*>(&As_[row * 32 + s * 8]); \
        }                                                                   \
        _Pragma("unroll")                                                   \
        for (int n = 0; n < 4; n++) {                                       \
            int row = wc * 64 + n * 16 + l16;                               \
            int s = lq ^ ((row >> 1) & 3);                                  \
            bgf[n] = *reinterpret_cast<const bf16x8*>(&Bg_[row * 32 + s * 8]); \
            buf_[n] = *reinterpret_cast<const bf16x8*>(&Bu_[row * 32 + s * 8]); \
        }                                                                   \
        _Pragma("unroll")                                                   \
        for (int m = 0; m < 4; m++)                                         \
            _Pragma("unroll")                                               \
            for (int n = 0; n < 4; n++) {                                   \
                accg[m][n] = __builtin_amdgcn_mfma_f32_16x16x32_bf16(af[m], bgf[n], accg[m][n], 0, 0, 0); \
                accu[m][n] = __builtin_amdgcn_mfma_f32_16x16x32_bf16(af[m], buf_[n], accu[m][n], 0, 0, 0); \
            }                                                               \
    }

    STAGE1(buf0, 0);
    __syncthreads();
    for (int k = 0; k < Hdim; k += 64) {
        STAGE1(buf1, k + 32);      // issue next half-tile; lands under COMP below
        COMP1(buf0);
        __syncthreads();           // waits buf1 loads (latency covered by MFMA)
        if (k + 64 < Hdim) STAGE1(buf0, k + 64);
        COMP1(buf1);
        __syncthreads();
    }

    // epilogue: silu(g)*u -> hact. C layout: col=lane&15, row=(lane>>4)*4+reg
    const int colbase = ytile * 128 + wc * 64;
#pragma unroll
    for (int m = 0; m < 4; m++) {
        int lr0 = m0 + wr * 64 + m * 16 + lq * 4;
#pragma unroll
        for (int j = 0; j < 4; j++) {
            int lr = lr0 + j;
            if (lr < n_e) {
                size_t rowoff = (size_t)(base + lr) * Idim;
#pragma unroll
                for (int n = 0; n < 4; n++) {
                    float g = accg[m][n][j], u = accu[m][n][j];
                    float v = (g / (1.f + __expf(-g))) * u;
                    hact[rowoff + colbase + n * 16 + l16] = (bf16)v;
                }
            }
        }
    }
#undef STAGE1
#undef COMP1
}

// ---------------- GEMM2: y = hact * down_proj[e]^T, weighted scatter-add ----------------
// Flat grid 8192 = 64 m-slots x 16 y-tiles x 8 experts. XCD-chunk swizzle.
// BK=32, named dbuf (2 x 16KB), 4 blocks/CU -> 128 slots/XCD == 128 real blocks.

__global__ __launch_bounds__(256, 4) void k_gemm2(
    const bf16* __restrict__ hact, const bf16* __restrict__ dpb,
    const int* __restrict__ meta, const float* __restrict__ weightv,
    float* __restrict__ out) {
    const int flat = blockIdx.x;
    const int work = (flat & 7) * 1024 + (flat >> 3);
    const int mslot = work & 63;
    const int grp = work >> 6;        // [0,128)
    const int e = grp >> 4;
    const int ytile = grp & 15;

    const int n_e = meta[e];
    const int m0 = mslot * 128;
    if (m0 >= n_e) return;
    const int base = meta[8 + e];
    const int* toks = (const int*)(meta + 64) + base;
    const bf16* wb = dpb + (size_t)e * Hdim * Idim + (size_t)(ytile * 128) * Idim;

    // per buffer (elements): A [0,4096) | B [4096,8192)
    __shared__ bf16 c0[8192];
    __shared__ bf16 c1[8192];

    const int tid = threadIdx.x;
    const int lane = tid & 63;
    const int wid = tid >> 6;
    const int wr = wid >> 1, wc = wid & 1;
    const int l16 = lane & 15, lq = lane >> 4;

    const bf16* gp[4];
    int lo[4];
#pragma unroll
    for (int r = 0; r < 4; r++) {
        int rr = r & 1;
        int s = rr * 256 + tid;
        int row = s >> 2, seg = s & 3;
        int ss = seg ^ ((row >> 1) & 3);
        lo[r] = (r >> 1) * 8192 + (rr * 256 + (tid & ~63)) * 16;
        if (r < 2) {
            int rm = m0 + row;
            if (rm >= n_e) rm = n_e - 1;
            gp[r] = hact + (size_t)(base + rm) * Idim + ss * 8;
        } else {
            gp[r] = wb + (size_t)row * Idim + ss * 8;
        }
    }

    f32x4 acc[4][4];
#pragma unroll
    for (int m = 0; m < 4; m++)
#pragma unroll
        for (int n = 0; n < 4; n++) acc[m][n] = f32x4{0.f, 0.f, 0.f, 0.f};

#define STAGE2(BUF, K0)                                                     \
    {                                                                       \
        _Pragma("unroll")                                                   \
        for (int r = 0; r < 4; r++) GLOAD16(gp[r] + (K0), (char*)(BUF) + lo[r]); \
    }

#define COMP2(BUF)                                                          \
    {                                                                       \
        const bf16* As_ = (BUF);                                            \
        const bf16* Bs_ = (BUF) + 4096;                                     \
        bf16x8 af[4], bf_[4];                                               \
        _Pragma("unroll")                                                   \
        for (int m = 0; m < 4; m++) {                                       \
            int row = wr * 64 + m * 16 + l16;                               \
            int s = lq ^ ((row >> 1) & 3);                                  \
            af[m] = *reinterpret_cast<const bf16x8*>(&As_[row * 32 + s * 8]); \
        }                                                                   \
        _Pragma("unroll")                                                   \
        for (int n = 0; n < 4; n++) {                                       \
            int row = wc * 64 + n * 16 + l16;                               \
            int s = lq ^ ((row >> 1) & 3);                                  \
            bf_[n] = *reinterpret_cast<const bf16x8*>(&Bs_[row * 32 + s * 8]); \
        }                                                                   \
        _Pragma("unroll")                                                   \
        for (int m = 0; m < 4; m++)                                         \
            _Pragma("unroll")                                               \
            for (int n = 0; n < 4; n++)                                     \
                acc[m][n] = __builtin_amdgcn_mfma_f32_16x16x32_bf16(af[m], bf_[n], acc[m][n], 0, 0, 0); \
    }

    STAGE2(c0, 0);
    __syncthreads();
    for (int k = 0; k < Idim; k += 64) {
        STAGE2(c1, k + 32);
        COMP2(c0);
        __syncthreads();
        if (k + 64 < Idim) STAGE2(c0, k + 64);
        COMP2(c1);
        __syncthreads();
    }

    const int colbase = ytile * 128 + wc * 64;
#pragma unroll
    for (int m = 0; m < 4; m++) {
        int lr0 = m0 + wr * 64 + m * 16 + lq * 4;
#pragma unroll
        for (int j = 0; j < 4; j++) {
            int lr = lr0 + j;
            if (lr < n_e) {
                int tok = toks[lr];
                float w = weightv[base + lr];
#pragma unroll
                for (int n = 0; n < 4; n++) {
                    float v = acc[m][n][j] * w;
                    unsafeAtomicAdd(&out[(size_t)tok * Hdim + colbase + n * 16 + l16], v);
                }
            }
        }
    }
#undef STAGE2
#undef COMP2
}

// ---------------- launch ----------------

extern "C" void kernel_launch(void* const* d_in, const int* in_sizes, int n_in,
                              void* d_out, int out_size, void* d_ws, size_t ws_size,
                              hipStream_t stream) {
    const float* x = (const float*)d_in[0];
    const int* eidx = (const int*)d_in[1];
    const float* ewts = (const float*)d_in[2];
    const float* w13 = (const float*)d_in[3];
    const float* dproj = (const float*)d_in[4];
    float* out = (float*)d_out;

    // ws layout (bytes): ints block [0, 67840), then bf16 buffers (16B-aligned)
    char* ws = (char*)d_ws;
    int* meta = (int*)ws;                       // [0..7] counts, [8..15] offsets
    int* token_id = meta + 64;                  // [NPAIR]
    float* weightv = (float*)(meta + 64 + NPAIR);
    int* chunkhist = meta + 64 + 2 * NPAIR;     // [32*NE]
    int* chunkbase = chunkhist + 256;           // [32*NE]
    bf16* xb = (bf16*)(ws + 67840);             // [NT][Hdim]
    bf16* w13b = xb + (size_t)NT * Hdim;        // [NE][2*Idim][Hdim]
    bf16* dpb = w13b + (size_t)NE * 2 * Idim * Hdim;  // [NE][Hdim][Idim]
    bf16* hact = dpb + (size_t)NE * Hdim * Idim;      // [NPAIR][Idim]

    hipMemsetAsync(d_out, 0, (size_t)out_size * sizeof(float), stream);

    const int nx8 = NT * Hdim / 8;                    // 1048576
    const int nw8 = NE * 2 * Idim * Hdim / 8;         // 5767168
    const int nd8 = NE * Hdim * Idim / 8;             // 2883584
    k_cvt<<<(nx8 + 255) / 256, 256, 0, stream>>>(x, xb, nx8);
    k_cvt<<<(nw8 + 255) / 256, 256, 0, stream>>>(w13, w13b, nw8);
    k_cvt<<<(nd8 + 255) / 256, 256, 0, stream>>>(dproj, dpb, nd8);

    k_bin1<<<32, 256, 0, stream>>>(eidx, chunkhist);
    k_bin2<<<1, 64, 0, stream>>>(meta, chunkhist, chunkbase);
    k_bin3<<<32, 256, 0, stream>>>(eidx, ewts, meta, chunkbase, token_id, weightv);

    k_gemm1<<<5632, 256, 0, stream>>>(xb, w13b, meta, hact);
    k_gemm2<<<8192, 256, 0, stream>>>(hact, dpb, meta, weightv, out);
}

// Round 12
// 510.291 us; speedup vs baseline: 1.5725x; 1.5725x over previous
//
#include <hip/hip_runtime.h>
#include <hip/hip_bf16.h>

// MoE SwiGLU: H=2048, I=1408, E=8, TOPK=2, T=4096 tokens (8192 pairs).
// R12 = R9/R10/R11 resubmitted unchanged (all died on infra:
// UnresponsiveContainer, same wedged container; kernel never executed).
// R9 = R7 structure VERBATIM (bf16 preconvert + global_load_lds BK=64 +
// XCD-chunk swizzle + sync;STAGE;sync;COMP loop), tiles scaled M 128->256:
//  - gemm1: 256M x (128g+128u), 512 thr, LDS 64KB, 2 blocks/CU -> one round/XCD
//  - gemm2: 256M x 128N, 256 thr, LDS 48KB, 3 blocks/CU -> one round/XCD

typedef __bf16 bf16;
typedef bf16 bf16x8 __attribute__((ext_vector_type(8)));
typedef float f32x4 __attribute__((ext_vector_type(4)));

constexpr int Hdim = 2048;
constexpr int Idim = 1408;
constexpr int NE = 8;
constexpr int TOPK = 2;
constexpr int NT = 4096;      // tokens
constexpr int NPAIR = 8192;   // T * TOPK
constexpr int BK = 64;

#define GLOAD16(G, L) __builtin_amdgcn_global_load_lds(                    \
    (const __attribute__((address_space(1))) void*)(G),                    \
    (__attribute__((address_space(3))) void*)(L), 16, 0, 0)

// ---------------- f32 -> bf16 convert (streaming) ----------------

__global__ void k_cvt(const float* __restrict__ src, bf16* __restrict__ dst, int n8) {
    int i = blockIdx.x * 256 + threadIdx.x;
    if (i >= n8) return;
    f32x4 a = *reinterpret_cast<const f32x4*>(src + (size_t)i * 8);
    f32x4 b = *reinterpret_cast<const f32x4*>(src + (size_t)i * 8 + 4);
    bf16x8 v;
#pragma unroll
    for (int j = 0; j < 4; j++) { v[j] = (bf16)a[j]; v[4 + j] = (bf16)b[j]; }
    *reinterpret_cast<bf16x8*>(dst + (size_t)i * 8) = v;
}

// ---------------- binning (deterministic) ----------------

__global__ void k_bin1(const int* __restrict__ eidx, int* __restrict__ chunkhist) {
    __shared__ int h[NE];
    int t = threadIdx.x;
    if (t < NE) h[t] = 0;
    __syncthreads();
    int p = blockIdx.x * 256 + t;
    atomicAdd(&h[eidx[p]], 1);
    __syncthreads();
    if (t < NE) chunkhist[blockIdx.x * NE + t] = h[t];
}

__global__ void k_bin2(int* __restrict__ meta, const int* __restrict__ chunkhist,
                       int* __restrict__ chunkbase) {
    if (threadIdx.x == 0) {
        int counts[NE];
        for (int e = 0; e < NE; e++) counts[e] = 0;
        for (int b = 0; b < 32; b++)
            for (int e = 0; e < NE; e++) {
                chunkbase[b * NE + e] = counts[e];
                counts[e] += chunkhist[b * NE + e];
            }
        int acc = 0;
        for (int e = 0; e < NE; e++) {
            meta[e] = counts[e];      // counts
            meta[8 + e] = acc;        // exclusive offsets
            acc += counts[e];
        }
    }
}

__global__ void k_bin3(const int* __restrict__ eidx, const float* __restrict__ wts,
                       const int* __restrict__ meta, const int* __restrict__ chunkbase,
                       int* __restrict__ token_id, float* __restrict__ weightv) {
    __shared__ int earr[256];
    int t = threadIdx.x;
    int p = blockIdx.x * 256 + t;
    int e = eidx[p];
    earr[t] = e;
    __syncthreads();
    int rank = 0;
    for (int q = 0; q < t; q++) rank += (earr[q] == e) ? 1 : 0;
    int pos = meta[8 + e] + chunkbase[blockIdx.x * NE + e] + rank;
    token_id[pos] = p / TOPK;
    weightv[pos] = wts[p];
}

// ---------------- GEMM1: gu = X_e * w13[e]^T, fused SwiGLU ----------------
// Flat grid 2816 = 32 m-slots x 11 y-tiles x 8 experts. XCD-chunk swizzle:
// work = (flat%8)*352 + flat/8 -> XCD k runs groups [11k,11k+11) = expert k.
// 512 threads = 8 waves (2Mr x 4Nc); wave tile 128M x 32I (g and u).

__global__ __launch_bounds__(512, 2) void k_gemm1(
    const bf16* __restrict__ xb, const bf16* __restrict__ w13b,
    const int* __restrict__ meta, bf16* __restrict__ hact) {
    const int flat = blockIdx.x;
    const int work = (flat & 7) * 352 + (flat >> 3);
    const int mslot = work & 31;
    const int grp = work >> 5;        // [0,88)
    const int e = grp / 11;
    const int ytile = grp - e * 11;

    const int n_e = meta[e];
    const int m0 = mslot * 256;
    if (m0 >= n_e) return;
    const int base = meta[8 + e];
    const int* toks = (const int*)(meta + 64) + base;
    const bf16* wg = w13b + (size_t)e * (2 * Idim) * Hdim + (size_t)(ytile * 128) * Hdim;
    const bf16* wu = wg + (size_t)Idim * Hdim;

    // elems: A [0,16384) | Bg [16384,24576) | Bu [24576,32768)  (64 KB)
    __shared__ bf16 smem[32768];

    const int tid = threadIdx.x;
    const int lane = tid & 63;
    const int wid = tid >> 6;
    const int wr = wid >> 2, wc = wid & 3;    // 2M x 4N waves
    const int l16 = lane & 15, lq = lane >> 4;

    // staging: A = 2048 slots of 16B (4 rounds x 512 thr), Bg/Bu = 1024 slots
    // (2 rounds each). LDS dest LINEAR; global seg pre-swizzled s^(row&7).
    const bf16* gp[8];
    int lo[8];
#pragma unroll
    for (int r = 0; r < 8; r++) {
        int q = (r < 4) ? r : ((r - 4) & 1);
        int sid = q * 512 + tid;
        int row = sid >> 3, seg = sid & 7;
        int ss = seg ^ (row & 7);
        if (r < 4) {
            lo[r] = (r * 512 + (tid & ~63)) * 16;
            int rm = m0 + row;
            if (rm >= n_e) rm = n_e - 1;          // clamp keeps reads in-bounds
            gp[r] = xb + (size_t)toks[rm] * Hdim + ss * 8;
        } else if (r < 6) {
            lo[r] = 32768 + ((r - 4) * 512 + (tid & ~63)) * 16;
            gp[r] = wg + (size_t)row * Hdim + ss * 8;
        } else {
            lo[r] = 49152 + ((r - 6) * 512 + (tid & ~63)) * 16;
            gp[r] = wu + (size_t)row * Hdim + ss * 8;
        }
    }

    f32x4 accg[8][2], accu[8][2];
#pragma unroll
    for (int m = 0; m < 8; m++)
#pragma unroll
        for (int n = 0; n < 2; n++) {
            accg[m][n] = f32x4{0.f, 0.f, 0.f, 0.f};
            accu[m][n] = f32x4{0.f, 0.f, 0.f, 0.f};
        }

    for (int k0 = 0; k0 < Hdim; k0 += BK) {
        __syncthreads();
#pragma unroll
        for (int r = 0; r < 8; r++) GLOAD16(gp[r] + k0, (char*)smem + lo[r]);
        __syncthreads();
        const bf16* As = smem;
        const bf16* Bg = smem + 16384;
        const bf16* Bu = smem + 24576;
#pragma unroll
        for (int kk = 0; kk < 2; ++kk) {
            bf16x8 af[8], bgf[2], buf_[2];
#pragma unroll
            for (int m = 0; m < 8; m++) {
                int row = wr * 128 + m * 16 + l16;
                int s = (kk * 4 + lq) ^ (row & 7);
                af[m] = *reinterpret_cast<const bf16x8*>(&As[row * 64 + s * 8]);
            }
#pragma unroll
            for (int n = 0; n < 2; n++) {
                int row = wc * 32 + n * 16 + l16;
                int s = (kk * 4 + lq) ^ (row & 7);
                bgf[n] = *reinterpret_cast<const bf16x8*>(&Bg[row * 64 + s * 8]);
                buf_[n] = *reinterpret_cast<const bf16x8*>(&Bu[row * 64 + s * 8]);
            }
#pragma unroll
            for (int m = 0; m < 8; m++)
#pragma unroll
                for (int n = 0; n < 2; n++) {
                    accg[m][n] = __builtin_amdgcn_mfma_f32_16x16x32_bf16(af[m], bgf[n], accg[m][n], 0, 0, 0);
                    accu[m][n] = __builtin_amdgcn_mfma_f32_16x16x32_bf16(af[m], buf_[n], accu[m][n], 0, 0, 0);
                }
        }
    }

    // epilogue: silu(g)*u -> hact. C layout: col=lane&15, row=(lane>>4)*4+reg
    const int colbase = ytile * 128 + wc * 32;
#pragma unroll
    for (int m = 0; m < 8; m++) {
        int lr0 = m0 + wr * 128 + m * 16 + lq * 4;
#pragma unroll
        for (int j = 0; j < 4; j++) {
            int lr = lr0 + j;
            if (lr < n_e) {
                size_t rowoff = (size_t)(base + lr) * Idim;
#pragma unroll
                for (int n = 0; n < 2; n++) {
                    float g = accg[m][n][j], u = accu[m][n][j];
                    float v = (g / (1.f + __expf(-g))) * u;
                    hact[rowoff + colbase + n * 16 + l16] = (bf16)v;
                }
            }
        }
    }
}

// ---------------- GEMM2: y = hact * down_proj[e]^T, weighted scatter-add ----------------
// Flat grid 4096 = 32 m-slots x 16 y-tiles x 8 experts. XCD-chunk swizzle:
// work = (flat%8)*512 + flat/8 -> XCD k runs expert k's 16 y-tiles.
// 256 threads = 4 waves (2x2); wave tile 128M x 64N; LDS 48KB -> 3 blocks/CU.

__global__ __launch_bounds__(256, 3) void k_gemm2(
    const bf16* __restrict__ hact, const bf16* __restrict__ dpb,
    const int* __restrict__ meta, const float* __restrict__ weightv,
    float* __restrict__ out) {
    const int flat = blockIdx.x;
    const int work = (flat & 7) * 512 + (flat >> 3);
    const int mslot = work & 31;
    const int grp = work >> 5;        // [0,128)
    const int e = grp >> 4;
    const int ytile = grp & 15;

    const int n_e = meta[e];
    const int m0 = mslot * 256;
    if (m0 >= n_e) return;
    const int base = meta[8 + e];
    const int* toks = (const int*)(meta + 64) + base;
    const bf16* wb = dpb + (size_t)e * Hdim * Idim + (size_t)(ytile * 128) * Idim;

    // elems: A [0,16384) | B [16384,24576)  (48 KB)
    __shared__ bf16 smem[24576];

    const int tid = threadIdx.x;
    const int lane = tid & 63;
    const int wid = tid >> 6;
    const int wr = wid >> 1, wc = wid & 1;
    const int l16 = lane & 15, lq = lane >> 4;

    // staging: A = 2048 slots (8 rounds x 256 thr), B = 1024 slots (4 rounds).
    const bf16* gp[12];
    int lo[12];
#pragma unroll
    for (int r = 0; r < 12; r++) {
        int q = (r < 8) ? r : (r - 8);
        int sid = q * 256 + tid;
        int row = sid >> 3, seg = sid & 7;
        int ss = seg ^ (row & 7);
        if (r < 8) {
            lo[r] = (r * 256 + (tid & ~63)) * 16;
            int rm = m0 + row;
            if (rm >= n_e) rm = n_e - 1;
            gp[r] = hact + (size_t)(base + rm) * Idim + ss * 8;
        } else {
            lo[r] = 32768 + ((r - 8) * 256 + (tid & ~63)) * 16;
            gp[r] = wb + (size_t)row * Idim + ss * 8;
        }
    }

    f32x4 acc[8][4];
#pragma unroll
    for (int m = 0; m < 8; m++)
#pragma unroll
        for (int n = 0; n < 4; n++) acc[m][n] = f32x4{0.f, 0.f, 0.f, 0.f};

    for (int k0 = 0; k0 < Idim; k0 += BK) {
        __syncthreads();
#pragma unroll
        for (int r = 0; r < 12; r++) GLOAD16(gp[r] + k0, (char*)smem + lo[r]);
        __syncthreads();
        const bf16* As = smem;
        const bf16* Bs = smem + 16384;
#pragma unroll
        for (int kk = 0; kk < 2; ++kk) {
            bf16x8 af[8], bf_[4];
#pragma unroll
            for (int m = 0; m < 8; m++) {
                int row = wr * 128 + m * 16 + l16;
                int s = (kk * 4 + lq) ^ (row & 7);
                af[m] = *reinterpret_cast<const bf16x8*>(&As[row * 64 + s * 8]);
            }
#pragma unroll
            for (int n = 0; n < 4; n++) {
                int row = wc * 64 + n * 16 + l16;
                int s = (kk * 4 + lq) ^ (row & 7);
                bf_[n] = *reinterpret_cast<const bf16x8*>(&Bs[row * 64 + s * 8]);
            }
#pragma unroll
            for (int m = 0; m < 8; m++)
#pragma unroll
                for (int n = 0; n < 4; n++)
                    acc[m][n] = __builtin_amdgcn_mfma_f32_16x16x32_bf16(af[m], bf_[n], acc[m][n], 0, 0, 0);
        }
    }

    const int colbase = ytile * 128 + wc * 64;
#pragma unroll
    for (int m = 0; m < 8; m++) {
        int lr0 = m0 + wr * 128 + m * 16 + lq * 4;
#pragma unroll
        for (int j = 0; j < 4; j++) {
            int lr = lr0 + j;
            if (lr < n_e) {
                int tok = toks[lr];
                float w = weightv[base + lr];
#pragma unroll
                for (int n = 0; n < 4; n++) {
                    float v = acc[m][n][j] * w;
                    unsafeAtomicAdd(&out[(size_t)tok * Hdim + colbase + n * 16 + l16], v);
                }
            }
        }
    }
}

// ---------------- launch ----------------

extern "C" void kernel_launch(void* const* d_in, const int* in_sizes, int n_in,
                              void* d_out, int out_size, void* d_ws, size_t ws_size,
                              hipStream_t stream) {
    const float* x = (const float*)d_in[0];
    const int* eidx = (const int*)d_in[1];
    const float* ewts = (const float*)d_in[2];
    const float* w13 = (const float*)d_in[3];
    const float* dproj = (const float*)d_in[4];
    float* out = (float*)d_out;

    // ws layout (bytes): ints block [0, 67840), then bf16 buffers (16B-aligned)
    char* ws = (char*)d_ws;
    int* meta = (int*)ws;                       // [0..7] counts, [8..15] offsets
    int* token_id = meta + 64;                  // [NPAIR]
    float* weightv = (float*)(meta + 64 + NPAIR);
    int* chunkhist = meta + 64 + 2 * NPAIR;     // [32*NE]
    int* chunkbase = chunkhist + 256;           // [32*NE]
    bf16* xb = (bf16*)(ws + 67840);             // [NT][Hdim]
    bf16* w13b = xb + (size_t)NT * Hdim;        // [NE][2*Idim][Hdim]
    bf16* dpb = w13b + (size_t)NE * 2 * Idim * Hdim;  // [NE][Hdim][Idim]
    bf16* hact = dpb + (size_t)NE * Hdim * Idim;      // [NPAIR][Idim]

    hipMemsetAsync(d_out, 0, (size_t)out_size * sizeof(float), stream);

    const int nx8 = NT * Hdim / 8;                    // 1048576
    const int nw8 = NE * 2 * Idim * Hdim / 8;         // 5767168
    const int nd8 = NE * Hdim * Idim / 8;             // 2883584
    k_cvt<<<(nx8 + 255) / 256, 256, 0, stream>>>(x, xb, nx8);
    k_cvt<<<(nw8 + 255) / 256, 256, 0, stream>>>(w13, w13b, nw8);
    k_cvt<<<(nd8 + 255) / 256, 256, 0, stream>>>(dproj, dpb, nd8);

    k_bin1<<<32, 256, 0, stream>>>(eidx, chunkhist);
    k_bin2<<<1, 64, 0, stream>>>(meta, chunkhist, chunkbase);
    k_bin3<<<32, 256, 0, stream>>>(eidx, ewts, meta, chunkbase, token_id, weightv);

    k_gemm1<<<2816, 512, 0, stream>>>(xb, w13b, meta, hact);
    k_gemm2<<<4096, 256, 0, stream>>>(hact, dpb, meta, weightv, out);
}

// Round 13
// 367.662 us; speedup vs baseline: 2.1825x; 1.3879x over previous
//
#include <hip/hip_runtime.h>
#include <hip/hip_bf16.h>

// MoE SwiGLU: H=2048, I=1408, E=8, TOPK=2, T=4096 tokens (8192 pairs).
// R13 = R7 verbatim (best measured: 354us; gemm1 163us control) EXCEPT
// gemm2 tile N 128->256 (M stays 128): MFMA/staged-byte 4.0 -> 5.33 per KB
// (matches gemm1) and one dispatch round per XCD (64 blocks on 64 slots).
// R12 lesson: M=256 scale-up regressed (bigger serialized stage phase, less
// cross-block overlap) -> keep 128M blocks, widen N only where ratio is poor.

typedef __bf16 bf16;
typedef bf16 bf16x8 __attribute__((ext_vector_type(8)));
typedef float f32x4 __attribute__((ext_vector_type(4)));

constexpr int Hdim = 2048;
constexpr int Idim = 1408;
constexpr int NE = 8;
constexpr int TOPK = 2;
constexpr int NT = 4096;      // tokens
constexpr int NPAIR = 8192;   // T * TOPK
constexpr int BK = 64;

#define GLOAD16(G, L) __builtin_amdgcn_global_load_lds(                    \
    (const __attribute__((address_space(1))) void*)(G),                    \
    (__attribute__((address_space(3))) void*)(L), 16, 0, 0)

// ---------------- f32 -> bf16 convert (streaming) ----------------

__global__ void k_cvt(const float* __restrict__ src, bf16* __restrict__ dst, int n8) {
    int i = blockIdx.x * 256 + threadIdx.x;
    if (i >= n8) return;
    f32x4 a = *reinterpret_cast<const f32x4*>(src + (size_t)i * 8);
    f32x4 b = *reinterpret_cast<const f32x4*>(src + (size_t)i * 8 + 4);
    bf16x8 v;
#pragma unroll
    for (int j = 0; j < 4; j++) { v[j] = (bf16)a[j]; v[4 + j] = (bf16)b[j]; }
    *reinterpret_cast<bf16x8*>(dst + (size_t)i * 8) = v;
}

// ---------------- binning (deterministic) ----------------

__global__ void k_bin1(const int* __restrict__ eidx, int* __restrict__ chunkhist) {
    __shared__ int h[NE];
    int t = threadIdx.x;
    if (t < NE) h[t] = 0;
    __syncthreads();
    int p = blockIdx.x * 256 + t;
    atomicAdd(&h[eidx[p]], 1);
    __syncthreads();
    if (t < NE) chunkhist[blockIdx.x * NE + t] = h[t];
}

__global__ void k_bin2(int* __restrict__ meta, const int* __restrict__ chunkhist,
                       int* __restrict__ chunkbase) {
    if (threadIdx.x == 0) {
        int counts[NE];
        for (int e = 0; e < NE; e++) counts[e] = 0;
        for (int b = 0; b < 32; b++)
            for (int e = 0; e < NE; e++) {
                chunkbase[b * NE + e] = counts[e];
                counts[e] += chunkhist[b * NE + e];
            }
        int acc = 0;
        for (int e = 0; e < NE; e++) {
            meta[e] = counts[e];      // counts
            meta[8 + e] = acc;        // exclusive offsets
            acc += counts[e];
        }
    }
}

__global__ void k_bin3(const int* __restrict__ eidx, const float* __restrict__ wts,
                       const int* __restrict__ meta, const int* __restrict__ chunkbase,
                       int* __restrict__ token_id, float* __restrict__ weightv) {
    __shared__ int earr[256];
    int t = threadIdx.x;
    int p = blockIdx.x * 256 + t;
    int e = eidx[p];
    earr[t] = e;
    __syncthreads();
    int rank = 0;
    for (int q = 0; q < t; q++) rank += (earr[q] == e) ? 1 : 0;
    int pos = meta[8 + e] + chunkbase[blockIdx.x * NE + e] + rank;
    token_id[pos] = p / TOPK;
    weightv[pos] = wts[p];
}

// ---------------- GEMM1: gu = X_e * w13[e]^T, fused SwiGLU (R7 verbatim) ----------------
// Flat grid 5632 = 64 m-slots x 11 y-tiles x 8 experts. XCD-chunk swizzle:
// work = (flat%8)*704 + flat/8 -> XCD k runs groups [11k, 11k+11) = expert k.

__global__ __launch_bounds__(256, 2) void k_gemm1(
    const bf16* __restrict__ xb, const bf16* __restrict__ w13b,
    const int* __restrict__ meta, bf16* __restrict__ hact) {
    const int flat = blockIdx.x;
    const int work = (flat & 7) * 704 + (flat >> 3);
    const int mslot = work & 63;
    const int grp = work >> 6;        // [0,88)
    const int e = grp / 11;
    const int ytile = grp - e * 11;

    const int n_e = meta[e];
    const int m0 = mslot * 128;
    if (m0 >= n_e) return;
    const int base = meta[8 + e];
    const int* toks = (const int*)(meta + 64) + base;
    const bf16* wg = w13b + (size_t)e * (2 * Idim) * Hdim + (size_t)(ytile * 128) * Hdim;
    const bf16* wu = wg + (size_t)Idim * Hdim;

    __shared__ bf16 As[128 * 64];
    __shared__ bf16 Bg[128 * 64];
    __shared__ bf16 Bu[128 * 64];

    const int tid = threadIdx.x;
    const int lane = tid & 63;
    const int wid = tid >> 6;
    const int wr = wid >> 1, wc = wid & 1;
    const int l16 = lane & 15, lq = lane >> 4;

    // staging: 1024 slots of 16B per tile, 4 rounds x 256 threads.
    // LDS dest LINEAR; global source pre-swizzled: LDS seg s of row r holds
    // global seg s^(r&7).
    const bf16* gA[4];
    const bf16* gG[4];
    const bf16* gU[4];
    int lo[4];
#pragma unroll
    for (int r = 0; r < 4; r++) {
        int sid = r * 256 + tid;
        int row = sid >> 3, seg = sid & 7;
        int ss = seg ^ (row & 7);
        lo[r] = (r * 256 + (tid & ~63)) * 16;   // wave-uniform LDS byte base
        int rr = m0 + row;
        if (rr >= n_e) rr = n_e - 1;            // clamp keeps reads in-bounds
        gA[r] = xb + (size_t)toks[rr] * Hdim + ss * 8;
        gG[r] = wg + (size_t)row * Hdim + ss * 8;
        gU[r] = wu + (size_t)row * Hdim + ss * 8;
    }

    f32x4 accg[4][4], accu[4][4];
#pragma unroll
    for (int m = 0; m < 4; m++)
#pragma unroll
        for (int n = 0; n < 4; n++) {
            accg[m][n] = f32x4{0.f, 0.f, 0.f, 0.f};
            accu[m][n] = f32x4{0.f, 0.f, 0.f, 0.f};
        }

    for (int k0 = 0; k0 < Hdim; k0 += BK) {
        __syncthreads();
#pragma unroll
        for (int r = 0; r < 4; r++) {
            GLOAD16(gA[r] + k0, (char*)As + lo[r]);
            GLOAD16(gG[r] + k0, (char*)Bg + lo[r]);
            GLOAD16(gU[r] + k0, (char*)Bu + lo[r]);
        }
        __syncthreads();
#pragma unroll
        for (int kk = 0; kk < 2; ++kk) {
            bf16x8 af[4], bgf[4], buf_[4];
#pragma unroll
            for (int m = 0; m < 4; m++) {
                int row = wr * 64 + m * 16 + l16;
                int s = (kk * 4 + lq) ^ (row & 7);
                af[m] = *reinterpret_cast<const bf16x8*>(&As[row * 64 + s * 8]);
            }
#pragma unroll
            for (int n = 0; n < 4; n++) {
                int row = wc * 64 + n * 16 + l16;
                int s = (kk * 4 + lq) ^ (row & 7);
                bgf[n] = *reinterpret_cast<const bf16x8*>(&Bg[row * 64 + s * 8]);
                buf_[n] = *reinterpret_cast<const bf16x8*>(&Bu[row * 64 + s * 8]);
            }
#pragma unroll
            for (int m = 0; m < 4; m++)
#pragma unroll
                for (int n = 0; n < 4; n++) {
                    accg[m][n] = __builtin_amdgcn_mfma_f32_16x16x32_bf16(af[m], bgf[n], accg[m][n], 0, 0, 0);
                    accu[m][n] = __builtin_amdgcn_mfma_f32_16x16x32_bf16(af[m], buf_[n], accu[m][n], 0, 0, 0);
                }
        }
    }

    // epilogue: silu(g)*u -> hact. C layout: col=lane&15, row=(lane>>4)*4+reg
    const int colbase = ytile * 128 + wc * 64;
#pragma unroll
    for (int m = 0; m < 4; m++) {
        int lr0 = m0 + wr * 64 + m * 16 + lq * 4;
#pragma unroll
        for (int j = 0; j < 4; j++) {
            int lr = lr0 + j;
            if (lr < n_e) {
                size_t rowoff = (size_t)(base + lr) * Idim;
#pragma unroll
                for (int n = 0; n < 4; n++) {
                    float g = accg[m][n][j], u = accu[m][n][j];
                    float v = (g / (1.f + __expf(-g))) * u;
                    hact[rowoff + colbase + n * 16 + l16] = (bf16)v;
                }
            }
        }
    }
}

// ---------------- GEMM2: y = hact * down_proj[e]^T, weighted scatter-add ----------------
// Tile 128M x 256N (widened from R7's 128x128). Flat grid 4096 = 64 m-slots x
// 8 y-tiles x 8 experts. XCD-chunk swizzle: work = (flat%8)*512 + flat/8.
// 256 threads = 4 waves (2M x 2N); wave tile 64M x 128N; acc[4][8].
// LDS 48KB (A 16KB + B 32KB); ~64 real blocks/XCD on 64 slots = one round.

__global__ __launch_bounds__(256, 2) void k_gemm2(
    const bf16* __restrict__ hact, const bf16* __restrict__ dpb,
    const int* __restrict__ meta, const float* __restrict__ weightv,
    float* __restrict__ out) {
    const int flat = blockIdx.x;
    const int work = (flat & 7) * 512 + (flat >> 3);
    const int mslot = work & 63;
    const int grp = work >> 6;        // [0,64)
    const int e = grp >> 3;
    const int ytile = grp & 7;

    const int n_e = meta[e];
    const int m0 = mslot * 128;
    if (m0 >= n_e) return;
    const int base = meta[8 + e];
    const int* toks = (const int*)(meta + 64) + base;
    const bf16* wb = dpb + (size_t)e * Hdim * Idim + (size_t)(ytile * 256) * Idim;

    // elems: A [0,8192) | B [8192,24576)  (48 KB)
    __shared__ bf16 smem[24576];

    const int tid = threadIdx.x;
    const int lane = tid & 63;
    const int wid = tid >> 6;
    const int wr = wid >> 1, wc = wid & 1;
    const int l16 = lane & 15, lq = lane >> 4;

    // staging: A = 1024 slots of 16B (4 rounds x 256 thr), B = 2048 slots
    // (8 rounds). LDS dest LINEAR; global seg pre-swizzled s^(row&7).
    const bf16* gp[12];
    int lo[12];
#pragma unroll
    for (int r = 0; r < 12; r++) {
        int q = (r < 4) ? r : (r - 4);
        int sid = q * 256 + tid;
        int row = sid >> 3, seg = sid & 7;
        int ss = seg ^ (row & 7);
        if (r < 4) {
            lo[r] = (r * 256 + (tid & ~63)) * 16;
            int rm = m0 + row;
            if (rm >= n_e) rm = n_e - 1;          // clamp keeps reads in-bounds
            gp[r] = hact + (size_t)(base + rm) * Idim + ss * 8;
        } else {
            lo[r] = 16384 + ((r - 4) * 256 + (tid & ~63)) * 16;
            gp[r] = wb + (size_t)row * Idim + ss * 8;
        }
    }

    f32x4 acc[4][8];
#pragma unroll
    for (int m = 0; m < 4; m++)
#pragma unroll
        for (int n = 0; n < 8; n++) acc[m][n] = f32x4{0.f, 0.f, 0.f, 0.f};

    for (int k0 = 0; k0 < Idim; k0 += BK) {
        __syncthreads();
#pragma unroll
        for (int r = 0; r < 12; r++) GLOAD16(gp[r] + k0, (char*)smem + lo[r]);
        __syncthreads();
        const bf16* As = smem;
        const bf16* Bs = smem + 8192;
#pragma unroll
        for (int kk = 0; kk < 2; ++kk) {
            bf16x8 af[4], bf_[8];
#pragma unroll
            for (int m = 0; m < 4; m++) {
                int row = wr * 64 + m * 16 + l16;
                int s = (kk * 4 + lq) ^ (row & 7);
                af[m] = *reinterpret_cast<const bf16x8*>(&As[row * 64 + s * 8]);
            }
#pragma unroll
            for (int n = 0; n < 8; n++) {
                int row = wc * 128 + n * 16 + l16;
                int s = (kk * 4 + lq) ^ (row & 7);
                bf_[n] = *reinterpret_cast<const bf16x8*>(&Bs[row * 64 + s * 8]);
            }
#pragma unroll
            for (int m = 0; m < 4; m++)
#pragma unroll
                for (int n = 0; n < 8; n++)
                    acc[m][n] = __builtin_amdgcn_mfma_f32_16x16x32_bf16(af[m], bf_[n], acc[m][n], 0, 0, 0);
        }
    }

    const int colbase = ytile * 256 + wc * 128;
#pragma unroll
    for (int m = 0; m < 4; m++) {
        int lr0 = m0 + wr * 64 + m * 16 + lq * 4;
#pragma unroll
        for (int j = 0; j < 4; j++) {
            int lr = lr0 + j;
            if (lr < n_e) {
                int tok = toks[lr];
                float w = weightv[base + lr];
#pragma unroll
                for (int n = 0; n < 8; n++) {
                    float v = acc[m][n][j] * w;
                    unsafeAtomicAdd(&out[(size_t)tok * Hdim + colbase + n * 16 + l16], v);
                }
            }
        }
    }
}

// ---------------- launch ----------------

extern "C" void kernel_launch(void* const* d_in, const int* in_sizes, int n_in,
                              void* d_out, int out_size, void* d_ws, size_t ws_size,
                              hipStream_t stream) {
    const float* x = (const float*)d_in[0];
    const int* eidx = (const int*)d_in[1];
    const float* ewts = (const float*)d_in[2];
    const float* w13 = (const float*)d_in[3];
    const float* dproj = (const float*)d_in[4];
    float* out = (float*)d_out;

    // ws layout (bytes): ints block [0, 67840), then bf16 buffers (16B-aligned)
    char* ws = (char*)d_ws;
    int* meta = (int*)ws;                       // [0..7] counts, [8..15] offsets
    int* token_id = meta + 64;                  // [NPAIR]
    float* weightv = (float*)(meta + 64 + NPAIR);
    int* chunkhist = meta + 64 + 2 * NPAIR;     // [32*NE]
    int* chunkbase = chunkhist + 256;           // [32*NE]
    bf16* xb = (bf16*)(ws + 67840);             // [NT][Hdim]
    bf16* w13b = xb + (size_t)NT * Hdim;        // [NE][2*Idim][Hdim]
    bf16* dpb = w13b + (size_t)NE * 2 * Idim * Hdim;  // [NE][Hdim][Idim]
    bf16* hact = dpb + (size_t)NE * Hdim * Idim;      // [NPAIR][Idim]

    hipMemsetAsync(d_out, 0, (size_t)out_size * sizeof(float), stream);

    const int nx8 = NT * Hdim / 8;                    // 1048576
    const int nw8 = NE * 2 * Idim * Hdim / 8;         // 5767168
    const int nd8 = NE * Hdim * Idim / 8;             // 2883584
    k_cvt<<<(nx8 + 255) / 256, 256, 0, stream>>>(x, xb, nx8);
    k_cvt<<<(nw8 + 255) / 256, 256, 0, stream>>>(w13, w13b, nw8);
    k_cvt<<<(nd8 + 255) / 256, 256, 0, stream>>>(dproj, dpb, nd8);

    k_bin1<<<32, 256, 0, stream>>>(eidx, chunkhist);
    k_bin2<<<1, 64, 0, stream>>>(meta, chunkhist, chunkbase);
    k_bin3<<<32, 256, 0, stream>>>(eidx, ewts, meta, chunkbase, token_id, weightv);

    k_gemm1<<<5632, 256, 0, stream>>>(xb, w13b, meta, hact);
    k_gemm2<<<4096, 256, 0, stream>>>(hact, dpb, meta, weightv, out);
}

// Round 14
// 351.789 us; speedup vs baseline: 2.2810x; 1.0451x over previous
//
#include <hip/hip_runtime.h>
#include <hip/hip_bf16.h>

// MoE SwiGLU: H=2048, I=1408, E=8, TOPK=2, T=4096 tokens (8192 pairs).
// R14 = R7 verbatim (the measured optimum of the 2-barrier family: 354us;
// gemm1 163 / gemm2 ~105 / cvt ~74 / memset+bins ~13) with two riskless trims:
//  - gemm2 reverted to R7's 128x128 (R13's 128x256 regressed: stage-bytes/step
//    dominate this template; bigger tiles lose).
//  - m-slot grids trimmed 64->16 (n_e ~ 1024+-30; 2048-row capacity = ~30 sigma):
//    gemm1 grid 5632->1408, gemm2 8192->2048; ~75% dead blocks removed.

typedef __bf16 bf16;
typedef bf16 bf16x8 __attribute__((ext_vector_type(8)));
typedef float f32x4 __attribute__((ext_vector_type(4)));

constexpr int Hdim = 2048;
constexpr int Idim = 1408;
constexpr int NE = 8;
constexpr int TOPK = 2;
constexpr int NT = 4096;      // tokens
constexpr int NPAIR = 8192;   // T * TOPK
constexpr int BK = 64;

#define GLOAD16(G, L) __builtin_amdgcn_global_load_lds(                    \
    (const __attribute__((address_space(1))) void*)(G),                    \
    (__attribute__((address_space(3))) void*)(L), 16, 0, 0)

// ---------------- f32 -> bf16 convert (streaming) ----------------

__global__ void k_cvt(const float* __restrict__ src, bf16* __restrict__ dst, int n8) {
    int i = blockIdx.x * 256 + threadIdx.x;
    if (i >= n8) return;
    f32x4 a = *reinterpret_cast<const f32x4*>(src + (size_t)i * 8);
    f32x4 b = *reinterpret_cast<const f32x4*>(src + (size_t)i * 8 + 4);
    bf16x8 v;
#pragma unroll
    for (int j = 0; j < 4; j++) { v[j] = (bf16)a[j]; v[4 + j] = (bf16)b[j]; }
    *reinterpret_cast<bf16x8*>(dst + (size_t)i * 8) = v;
}

// ---------------- binning (deterministic) ----------------

__global__ void k_bin1(const int* __restrict__ eidx, int* __restrict__ chunkhist) {
    __shared__ int h[NE];
    int t = threadIdx.x;
    if (t < NE) h[t] = 0;
    __syncthreads();
    int p = blockIdx.x * 256 + t;
    atomicAdd(&h[eidx[p]], 1);
    __syncthreads();
    if (t < NE) chunkhist[blockIdx.x * NE + t] = h[t];
}

__global__ void k_bin2(int* __restrict__ meta, const int* __restrict__ chunkhist,
                       int* __restrict__ chunkbase) {
    if (threadIdx.x == 0) {
        int counts[NE];
        for (int e = 0; e < NE; e++) counts[e] = 0;
        for (int b = 0; b < 32; b++)
            for (int e = 0; e < NE; e++) {
                chunkbase[b * NE + e] = counts[e];
                counts[e] += chunkhist[b * NE + e];
            }
        int acc = 0;
        for (int e = 0; e < NE; e++) {
            meta[e] = counts[e];      // counts
            meta[8 + e] = acc;        // exclusive offsets
            acc += counts[e];
        }
    }
}

__global__ void k_bin3(const int* __restrict__ eidx, const float* __restrict__ wts,
                       const int* __restrict__ meta, const int* __restrict__ chunkbase,
                       int* __restrict__ token_id, float* __restrict__ weightv) {
    __shared__ int earr[256];
    int t = threadIdx.x;
    int p = blockIdx.x * 256 + t;
    int e = eidx[p];
    earr[t] = e;
    __syncthreads();
    int rank = 0;
    for (int q = 0; q < t; q++) rank += (earr[q] == e) ? 1 : 0;
    int pos = meta[8 + e] + chunkbase[blockIdx.x * NE + e] + rank;
    token_id[pos] = p / TOPK;
    weightv[pos] = wts[p];
}

// ---------------- GEMM1: gu = X_e * w13[e]^T, fused SwiGLU (R7 verbatim) ----------------
// Flat grid 1408 = 16 m-slots x 11 y-tiles x 8 experts. XCD-chunk swizzle:
// work = (flat%8)*176 + flat/8; grp = work>>4 in [11k, 11k+11) on XCD k.

__global__ __launch_bounds__(256, 2) void k_gemm1(
    const bf16* __restrict__ xb, const bf16* __restrict__ w13b,
    const int* __restrict__ meta, bf16* __restrict__ hact) {
    const int flat = blockIdx.x;
    const int work = (flat & 7) * 176 + (flat >> 3);
    const int mslot = work & 15;
    const int grp = work >> 4;        // [0,88)
    const int e = grp / 11;
    const int ytile = grp - e * 11;

    const int n_e = meta[e];
    const int m0 = mslot * 128;
    if (m0 >= n_e) return;
    const int base = meta[8 + e];
    const int* toks = (const int*)(meta + 64) + base;
    const bf16* wg = w13b + (size_t)e * (2 * Idim) * Hdim + (size_t)(ytile * 128) * Hdim;
    const bf16* wu = wg + (size_t)Idim * Hdim;

    __shared__ bf16 As[128 * 64];
    __shared__ bf16 Bg[128 * 64];
    __shared__ bf16 Bu[128 * 64];

    const int tid = threadIdx.x;
    const int lane = tid & 63;
    const int wid = tid >> 6;
    const int wr = wid >> 1, wc = wid & 1;
    const int l16 = lane & 15, lq = lane >> 4;

    // staging: 1024 slots of 16B per tile, 4 rounds x 256 threads.
    // LDS dest LINEAR; global source pre-swizzled: LDS seg s of row r holds
    // global seg s^(r&7).
    const bf16* gA[4];
    const bf16* gG[4];
    const bf16* gU[4];
    int lo[4];
#pragma unroll
    for (int r = 0; r < 4; r++) {
        int sid = r * 256 + tid;
        int row = sid >> 3, seg = sid & 7;
        int ss = seg ^ (row & 7);
        lo[r] = (r * 256 + (tid & ~63)) * 16;   // wave-uniform LDS byte base
        int rr = m0 + row;
        if (rr >= n_e) rr = n_e - 1;            // clamp keeps reads in-bounds
        gA[r] = xb + (size_t)toks[rr] * Hdim + ss * 8;
        gG[r] = wg + (size_t)row * Hdim + ss * 8;
        gU[r] = wu + (size_t)row * Hdim + ss * 8;
    }

    f32x4 accg[4][4], accu[4][4];
#pragma unroll
    for (int m = 0; m < 4; m++)
#pragma unroll
        for (int n = 0; n < 4; n++) {
            accg[m][n] = f32x4{0.f, 0.f, 0.f, 0.f};
            accu[m][n] = f32x4{0.f, 0.f, 0.f, 0.f};
        }

    for (int k0 = 0; k0 < Hdim; k0 += BK) {
        __syncthreads();
#pragma unroll
        for (int r = 0; r < 4; r++) {
            GLOAD16(gA[r] + k0, (char*)As + lo[r]);
            GLOAD16(gG[r] + k0, (char*)Bg + lo[r]);
            GLOAD16(gU[r] + k0, (char*)Bu + lo[r]);
        }
        __syncthreads();
#pragma unroll
        for (int kk = 0; kk < 2; ++kk) {
            bf16x8 af[4], bgf[4], buf_[4];
#pragma unroll
            for (int m = 0; m < 4; m++) {
                int row = wr * 64 + m * 16 + l16;
                int s = (kk * 4 + lq) ^ (row & 7);
                af[m] = *reinterpret_cast<const bf16x8*>(&As[row * 64 + s * 8]);
            }
#pragma unroll
            for (int n = 0; n < 4; n++) {
                int row = wc * 64 + n * 16 + l16;
                int s = (kk * 4 + lq) ^ (row & 7);
                bgf[n] = *reinterpret_cast<const bf16x8*>(&Bg[row * 64 + s * 8]);
                buf_[n] = *reinterpret_cast<const bf16x8*>(&Bu[row * 64 + s * 8]);
            }
#pragma unroll
            for (int m = 0; m < 4; m++)
#pragma unroll
                for (int n = 0; n < 4; n++) {
                    accg[m][n] = __builtin_amdgcn_mfma_f32_16x16x32_bf16(af[m], bgf[n], accg[m][n], 0, 0, 0);
                    accu[m][n] = __builtin_amdgcn_mfma_f32_16x16x32_bf16(af[m], buf_[n], accu[m][n], 0, 0, 0);
                }
        }
    }

    // epilogue: silu(g)*u -> hact. C layout: col=lane&15, row=(lane>>4)*4+reg
    const int colbase = ytile * 128 + wc * 64;
#pragma unroll
    for (int m = 0; m < 4; m++) {
        int lr0 = m0 + wr * 64 + m * 16 + lq * 4;
#pragma unroll
        for (int j = 0; j < 4; j++) {
            int lr = lr0 + j;
            if (lr < n_e) {
                size_t rowoff = (size_t)(base + lr) * Idim;
#pragma unroll
                for (int n = 0; n < 4; n++) {
                    float g = accg[m][n][j], u = accu[m][n][j];
                    float v = (g / (1.f + __expf(-g))) * u;
                    hact[rowoff + colbase + n * 16 + l16] = (bf16)v;
                }
            }
        }
    }
}

// ---------------- GEMM2: y = hact * down_proj[e]^T, weighted scatter-add ----------------
// R7 verbatim 128x128. Flat grid 2048 = 16 m-slots x 16 y-tiles x 8 experts.
// XCD-chunk swizzle: work = (flat%8)*256 + flat/8 -> XCD k runs expert k.

__global__ __launch_bounds__(256, 2) void k_gemm2(
    const bf16* __restrict__ hact, const bf16* __restrict__ dpb,
    const int* __restrict__ meta, const float* __restrict__ weightv,
    float* __restrict__ out) {
    const int flat = blockIdx.x;
    const int work = (flat & 7) * 256 + (flat >> 3);
    const int mslot = work & 15;
    const int grp = work >> 4;        // [0,128)
    const int e = grp >> 4;
    const int ytile = grp & 15;

    const int n_e = meta[e];
    const int m0 = mslot * 128;
    if (m0 >= n_e) return;
    const int base = meta[8 + e];
    const int* toks = (const int*)(meta + 64) + base;
    const bf16* wb = dpb + (size_t)e * Hdim * Idim + (size_t)(ytile * 128) * Idim;

    __shared__ bf16 As[128 * 64];
    __shared__ bf16 Bs[128 * 64];

    const int tid = threadIdx.x;
    const int lane = tid & 63;
    const int wid = tid >> 6;
    const int wr = wid >> 1, wc = wid & 1;
    const int l16 = lane & 15, lq = lane >> 4;

    const bf16* gA[4];
    const bf16* gB[4];
    int lo[4];
#pragma unroll
    for (int r = 0; r < 4; r++) {
        int sid = r * 256 + tid;
        int row = sid >> 3, seg = sid & 7;
        int ss = seg ^ (row & 7);
        lo[r] = (r * 256 + (tid & ~63)) * 16;
        int rr = m0 + row;
        if (rr >= n_e) rr = n_e - 1;
        gA[r] = hact + (size_t)(base + rr) * Idim + ss * 8;
        gB[r] = wb + (size_t)row * Idim + ss * 8;
    }

    f32x4 acc[4][4];
#pragma unroll
    for (int m = 0; m < 4; m++)
#pragma unroll
        for (int n = 0; n < 4; n++) acc[m][n] = f32x4{0.f, 0.f, 0.f, 0.f};

    for (int k0 = 0; k0 < Idim; k0 += BK) {
        __syncthreads();
#pragma unroll
        for (int r = 0; r < 4; r++) {
            GLOAD16(gA[r] + k0, (char*)As + lo[r]);
            GLOAD16(gB[r] + k0, (char*)Bs + lo[r]);
        }
        __syncthreads();
#pragma unroll
        for (int kk = 0; kk < 2; ++kk) {
            bf16x8 af[4], bf_[4];
#pragma unroll
            for (int m = 0; m < 4; m++) {
                int row = wr * 64 + m * 16 + l16;
                int s = (kk * 4 + lq) ^ (row & 7);
                af[m] = *reinterpret_cast<const bf16x8*>(&As[row * 64 + s * 8]);
            }
#pragma unroll
            for (int n = 0; n < 4; n++) {
                int row = wc * 64 + n * 16 + l16;
                int s = (kk * 4 + lq) ^ (row & 7);
                bf_[n] = *reinterpret_cast<const bf16x8*>(&Bs[row * 64 + s * 8]);
            }
#pragma unroll
            for (int m = 0; m < 4; m++)
#pragma unroll
                for (int n = 0; n < 4; n++)
                    acc[m][n] = __builtin_amdgcn_mfma_f32_16x16x32_bf16(af[m], bf_[n], acc[m][n], 0, 0, 0);
        }
    }

    const int colbase = ytile * 128 + wc * 64;
#pragma unroll
    for (int m = 0; m < 4; m++) {
        int lr0 = m0 + wr * 64 + m * 16 + lq * 4;
#pragma unroll
        for (int j = 0; j < 4; j++) {
            int lr = lr0 + j;
            if (lr < n_e) {
                int tok = toks[lr];
                float w = weightv[base + lr];
#pragma unroll
                for (int n = 0; n < 4; n++) {
                    float v = acc[m][n][j] * w;
                    unsafeAtomicAdd(&out[(size_t)tok * Hdim + colbase + n * 16 + l16], v);
                }
            }
        }
    }
}

// ---------------- launch ----------------

extern "C" void kernel_launch(void* const* d_in, const int* in_sizes, int n_in,
                              void* d_out, int out_size, void* d_ws, size_t ws_size,
                              hipStream_t stream) {
    const float* x = (const float*)d_in[0];
    const int* eidx = (const int*)d_in[1];
    const float* ewts = (const float*)d_in[2];
    const float* w13 = (const float*)d_in[3];
    const float* dproj = (const float*)d_in[4];
    float* out = (float*)d_out;

    // ws layout (bytes): ints block [0, 67840), then bf16 buffers (16B-aligned)
    char* ws = (char*)d_ws;
    int* meta = (int*)ws;                       // [0..7] counts, [8..15] offsets
    int* token_id = meta + 64;                  // [NPAIR]
    float* weightv = (float*)(meta + 64 + NPAIR);
    int* chunkhist = meta + 64 + 2 * NPAIR;     // [32*NE]
    int* chunkbase = chunkhist + 256;           // [32*NE]
    bf16* xb = (bf16*)(ws + 67840);             // [NT][Hdim]
    bf16* w13b = xb + (size_t)NT * Hdim;        // [NE][2*Idim][Hdim]
    bf16* dpb = w13b + (size_t)NE * 2 * Idim * Hdim;  // [NE][Hdim][Idim]
    bf16* hact = dpb + (size_t)NE * Hdim * Idim;      // [NPAIR][Idim]

    hipMemsetAsync(d_out, 0, (size_t)out_size * sizeof(float), stream);

    const int nx8 = NT * Hdim / 8;                    // 1048576
    const int nw8 = NE * 2 * Idim * Hdim / 8;         // 5767168
    const int nd8 = NE * Hdim * Idim / 8;             // 2883584
    k_cvt<<<(nx8 + 255) / 256, 256, 0, stream>>>(x, xb, nx8);
    k_cvt<<<(nw8 + 255) / 256, 256, 0, stream>>>(w13, w13b, nw8);
    k_cvt<<<(nd8 + 255) / 256, 256, 0, stream>>>(dproj, dpb, nd8);

    k_bin1<<<32, 256, 0, stream>>>(eidx, chunkhist);
    k_bin2<<<1, 64, 0, stream>>>(meta, chunkhist, chunkbase);
    k_bin3<<<32, 256, 0, stream>>>(eidx, ewts, meta, chunkbase, token_id, weightv);

    k_gemm1<<<1408, 256, 0, stream>>>(xb, w13b, meta, hact);
    k_gemm2<<<2048, 256, 0, stream>>>(hact, dpb, meta, weightv, out);
}